// Round 3
// baseline (10891.385 us; speedup 1.0000x reference)
//
#include <hip/hip_runtime.h>
#include <cstdint>
#include <cstddef>

// CriticGNN: GENConv(softmax aggr) + MLP/BN + mean-pool + head.
// ALL tensors fp32 (reference declares jnp.float32 everywhere; the "bf16"
// in the test's error label is hardcoded fstring text, not a dtype signal).
// Softmax aggregation without max-subtraction (msg in [1e-7,~8] so exp is
// safe): agg = sum(m*e^m)/sum(e^m) -> one edge pass, 2 fp32 atomics/(node,ch).
// Workspace overlays keep total at ~51.3 MB.

#define N_NODES 100000
#define N_EDGES 3200000
#define B_GRAPHS 64
#define F_INF 64
#define E_INF 16
#define A_DIM 13
#define H_DIM 32
#define O_DIM 64
#define EPS_GEN 1e-7f
#define EPS_BN 1e-5f

// ---- K1: node encoder h = x @ node_w + node_b  [N,64]x[64,32] -> [N,32]
__global__ __launch_bounds__(256) void k_node_enc(
        const float* __restrict__ x, const float* __restrict__ w,
        const float* __restrict__ b, float* __restrict__ h) {
    __shared__ float sW[F_INF * H_DIM];
    __shared__ float sB[H_DIM];
    __shared__ float sX[8 * F_INF];
    int tid = threadIdx.x;
    for (int i = tid; i < F_INF * H_DIM; i += 256) sW[i] = w[i];
    if (tid < H_DIM) sB[tid] = b[tid];
    int node0 = blockIdx.x * 8;
    const float2* xp = (const float2*)(x + (size_t)node0 * F_INF);
    float2 v = xp[tid];
    sX[2 * tid] = v.x;
    sX[2 * tid + 1] = v.y;
    __syncthreads();
    int nl = tid >> 5, ch = tid & 31;
    float acc = sB[ch];
    const float* xr = &sX[nl * F_INF];
#pragma unroll
    for (int k = 0; k < F_INF; k++) acc = fmaf(xr[k], sW[k * H_DIM + ch], acc);
    h[(size_t)(node0 + nl) * H_DIM + ch] = acc;
}

// ---- K2: edge pass. msg=relu(h[src]+ea@W+b)+eps; atomic e^m and m*e^m by dst.
__global__ __launch_bounds__(256) void k_edge(
        const int* __restrict__ ei, const float* __restrict__ ea,
        const float* __restrict__ ew, const float* __restrict__ eb,
        const float* __restrict__ h, float* __restrict__ sm,
        float* __restrict__ wsum) {
    __shared__ float sW[E_INF * H_DIM];
    __shared__ float sB[H_DIM];
    int tid = threadIdx.x;
    for (int i = tid; i < E_INF * H_DIM; i += 256) sW[i] = ew[i];
    if (tid < H_DIM) sB[tid] = eb[tid];
    __syncthreads();
    int e = blockIdx.x * 256 + tid;
    if (e >= N_EDGES) return;
    int s = ei[e];
    int d = ei[N_EDGES + e];
    float a[E_INF];
    const float4* eap = (const float4*)(ea + (size_t)e * E_INF);
#pragma unroll
    for (int t = 0; t < 4; t++) {
        float4 v = eap[t];
        a[4 * t] = v.x; a[4 * t + 1] = v.y; a[4 * t + 2] = v.z; a[4 * t + 3] = v.w;
    }
    float hr[H_DIM];
    const float4* hp = (const float4*)(h + (size_t)s * H_DIM);
#pragma unroll
    for (int t = 0; t < 8; t++) {
        float4 v = hp[t];
        hr[4 * t] = v.x; hr[4 * t + 1] = v.y; hr[4 * t + 2] = v.z; hr[4 * t + 3] = v.w;
    }
    float acc[H_DIM];
#pragma unroll
    for (int j = 0; j < H_DIM; j++) acc[j] = sB[j];
#pragma unroll
    for (int k = 0; k < E_INF; k++) {
        float av = a[k];
#pragma unroll
        for (int j = 0; j < H_DIM; j++) acc[j] = fmaf(av, sW[k * H_DIM + j], acc[j]);
    }
    float* smp = sm + (size_t)d * H_DIM;
    float* wsp = wsum + (size_t)d * H_DIM;
#pragma unroll
    for (int j = 0; j < H_DIM; j++) {
        float m = fmaxf(acc[j] + hr[j], 0.0f) + EPS_GEN;
        float ex = __expf(m);
        unsafeAtomicAdd(&smp[j], ex);
        unsafeAtomicAdd(&wsp[j], m * ex);
    }
}

// ---- K3: conv_out = wsum/sm + h  (in-place into h)
__global__ __launch_bounds__(256) void k_agg(
        const float* __restrict__ sm, const float* __restrict__ wsum,
        float* __restrict__ h) {
    int i = blockIdx.x * 256 + threadIdx.x;
    if (i >= N_NODES * H_DIM) return;
    float s = sm[i];
    float v = (s > 0.0f) ? (wsum[i] / s) : 0.0f;
    h[i] = v + h[i];
}

// ---- K4: fused Lin (+optional folded-BN+ReLU on input) (+optional BN-stats)
template <int IN_CH, bool BN_IN, bool STATS>
__global__ __launch_bounds__(256) void k_lin(
        const float* __restrict__ in, const float* __restrict__ w,
        const float* __restrict__ b, const float* __restrict__ ss,
        float* __restrict__ out, float* __restrict__ stats) {
    __shared__ float sW[IN_CH * O_DIM];
    __shared__ float sB[O_DIM];
    __shared__ float sS[IN_CH], sH[IN_CH];
    __shared__ float sX[4 * IN_CH];
    __shared__ float r1[256], r2[256];
    int tid = threadIdx.x;
    for (int i = tid; i < IN_CH * O_DIM; i += 256) sW[i] = w[i];
    if (tid < O_DIM) sB[tid] = b[tid];
    if constexpr (BN_IN) {
        if (tid < IN_CH) { sS[tid] = ss[tid]; sH[tid] = ss[64 + tid]; }
    }
    int ch = tid & 63, nl = tid >> 6;
    float s1 = 0.0f, s2 = 0.0f;
    const int ngroups = N_NODES / 4;  // 25000
    __syncthreads();
    for (int g = blockIdx.x; g < ngroups; g += gridDim.x) {
        int node0 = g * 4;
        __syncthreads();
        for (int i = tid; i < 4 * IN_CH; i += 256) {
            float v = in[(size_t)node0 * IN_CH + i];
            if constexpr (BN_IN) {
                int c = i & (IN_CH - 1);
                v = fmaxf(fmaf(v, sS[c], sH[c]), 0.0f);
            }
            sX[i] = v;
        }
        __syncthreads();
        float acc = sB[ch];
        const float* xr = &sX[nl * IN_CH];
#pragma unroll
        for (int k = 0; k < IN_CH; k++) acc = fmaf(xr[k], sW[k * O_DIM + ch], acc);
        out[(size_t)(node0 + nl) * O_DIM + ch] = acc;
        if constexpr (STATS) { s1 += acc; s2 += acc * acc; }
    }
    if constexpr (STATS) {
        __syncthreads();
        r1[tid] = s1; r2[tid] = s2;
        __syncthreads();
        if (tid < 64) {
            float a1 = r1[tid] + r1[tid + 64] + r1[tid + 128] + r1[tid + 192];
            float a2 = r2[tid] + r2[tid + 64] + r2[tid + 128] + r2[tid + 192];
            unsafeAtomicAdd(&stats[tid], a1);
            unsafeAtomicAdd(&stats[64 + tid], a2);
        }
    }
}

// ---- K5: finalize BN stats -> folded scale/shift
__global__ void k_bnfin(const float* __restrict__ stats, const float* __restrict__ g,
                        const float* __restrict__ b, float* __restrict__ ss) {
    int c = threadIdx.x;
    if (c >= 64) return;
    const float invN = 1.0f / (float)N_NODES;
    float mu = stats[c] * invN;
    float var = fmaxf(stats[64 + c] * invN - mu * mu, 0.0f);
    float rs = 1.0f / sqrtf(var + EPS_BN);
    float sc = g[c] * rs;
    ss[c] = sc;
    ss[64 + c] = b[c] - mu * sc;
}

// ---- K6: graph boundaries via binary search over sorted batch
__global__ void k_bounds(const int* __restrict__ batch, int* __restrict__ start) {
    int g = threadIdx.x;
    if (g > B_GRAPHS) return;
    int lo = 0, hi = N_NODES;
    while (lo < hi) {
        int mid = (lo + hi) >> 1;
        if (batch[mid] < g) lo = mid + 1; else hi = mid;
    }
    start[g] = lo;
}

// ---- K7: segmented mean-pool partials (4 blocks per graph)
__global__ __launch_bounds__(256) void k_pool(
        const float* __restrict__ no, const int* __restrict__ start,
        float* __restrict__ gsum) {
    int g = blockIdx.x >> 2, q = blockIdx.x & 3;
    int s0 = start[g], s1e = start[g + 1];
    int len = s1e - s0;
    int per = (len + 3) >> 2;
    int a = s0 + q * per;
    int bnd = min(s0 + (q + 1) * per, s1e);
    int ch = threadIdx.x & 63, nl = threadIdx.x >> 6;
    float acc = 0.0f;
    for (int n = a + nl; n < bnd; n += 4) acc += no[(size_t)n * O_DIM + ch];
    __shared__ float r[256];
    r[threadIdx.x] = acc;
    __syncthreads();
    if (threadIdx.x < 64) {
        float v = r[ch] + r[ch + 64] + r[ch + 128] + r[ch + 192];
        unsafeAtomicAdd(&gsum[g * O_DIM + ch], v);
    }
}

// ---- K8: head (one thread per graph)
__global__ void k_head(const float* __restrict__ gsum, const int* __restrict__ start,
                       const float* __restrict__ action,
                       const float* __restrict__ pinw, const float* __restrict__ pinb,
                       const float* __restrict__ phw, const float* __restrict__ phb,
                       const float* __restrict__ pow_, const float* __restrict__ pob,
                       float* __restrict__ outp) {
    int g = threadIdx.x;
    if (g >= B_GRAPHS) return;
    int cnt = start[g + 1] - start[g];
    float inv = 1.0f / (float)max(cnt, 1);
    float mol[64];
#pragma unroll
    for (int c = 0; c < 64; c++) mol[c] = gsum[g * 64 + c] * inv;
    float fp[16];
#pragma unroll
    for (int j = 0; j < 16; j++) {
        float a = pinb[j];
        for (int c = 0; c < 64; c++) a = fmaf(mol[c], pinw[c * 16 + j], a);
        fp[j] = fmaxf(a, 0.0f);
    }
    float pol[10];
#pragma unroll
    for (int j = 0; j < 10; j++) {
        float a = phb[j];
        for (int k = 0; k < 16; k++) a = fmaf(fp[k], phw[k * 10 + j], a);
        for (int k = 0; k < 13; k++) a = fmaf(action[g * 13 + k], phw[(16 + k) * 10 + j], a);
        pol[j] = fmaxf(a, 0.0f);
    }
    float o = pob[0];
#pragma unroll
    for (int j = 0; j < 10; j++) o = fmaf(pol[j], pow_[j], o);
    outp[g] = o;
}

extern "C" void kernel_launch(void* const* d_in, const int* in_sizes, int n_in,
                              void* d_out, int out_size, void* d_ws, size_t ws_size,
                              hipStream_t stream) {
    const float* x      = (const float*)d_in[0];
    const int*   ei     = (const int*)d_in[1];
    const float* ea     = (const float*)d_in[2];
    const int*   batch  = (const int*)d_in[3];
    const float* action = (const float*)d_in[4];
    const float* node_w = (const float*)d_in[5];
    const float* node_b = (const float*)d_in[6];
    const float* edge_w = (const float*)d_in[7];
    const float* edge_b = (const float*)d_in[8];
    const float* w1 = (const float*)d_in[9];   const float* b1 = (const float*)d_in[10];
    const float* g1 = (const float*)d_in[11];  const float* bb1 = (const float*)d_in[12];
    const float* w2 = (const float*)d_in[13];  const float* b2 = (const float*)d_in[14];
    const float* g2 = (const float*)d_in[15];  const float* bb2 = (const float*)d_in[16];
    const float* w3 = (const float*)d_in[17];  const float* b3 = (const float*)d_in[18];
    const float* g3 = (const float*)d_in[19];  const float* bb3 = (const float*)d_in[20];
    const float* w4 = (const float*)d_in[21];  const float* b4 = (const float*)d_in[22];
    const float* pinw = (const float*)d_in[23]; const float* pinb = (const float*)d_in[24];
    const float* phw  = (const float*)d_in[25]; const float* phb  = (const float*)d_in[26];
    const float* pow_ = (const float*)d_in[27]; const float* pob  = (const float*)d_in[28];

    // ---- workspace layout (floats). Zeroed prefix: stats+gsum+sm+wsum.
    const size_t NC = (size_t)N_NODES * H_DIM;  // 3.2M floats
    float* ws = (float*)d_ws;
    size_t off = 0;
    float* stats = ws + off; off += 512;            // S1@0,S2@128,S3@256
    float* gsum  = ws + off; off += B_GRAPHS * O_DIM;
    float* sm    = ws + off; off += NC;             // 12.8 MB
    float* wsum  = ws + off; off += NC;             // 12.8 MB
    size_t zero_elems = off;
    float* h     = ws + off; off += NC;             // 12.8 MB
    float* ext   = ws + off; off += NC;             // 12.8 MB (2nd half of t2)
    float* ssb   = ws + off; off += 512;            // folded scale/shift L1/L2/L3
    int*   start = (int*)(ws + off); off += 128;
    (void)ext;
    float* t1 = sm;  // 25.6 MB overlay (sm+wsum free after k_agg)
    float* t2 = h;   // 25.6 MB overlay (h free after MLP-P1, spans h+ext)

    hipMemsetAsync(d_ws, 0, zero_elems * sizeof(float), stream);

    k_node_enc<<<N_NODES / 8, 256, 0, stream>>>(x, node_w, node_b, h);
    k_edge<<<(N_EDGES + 255) / 256, 256, 0, stream>>>(ei, ea, edge_w, edge_b, h, sm, wsum);
    k_agg<<<(N_NODES * H_DIM + 255) / 256, 256, 0, stream>>>(sm, wsum, h);
    // MLP: P1 32->64 (stats1), P2/P3 64->64 (bn in, stats), P4 64->64 (bn in)
    k_lin<32, false, true><<<2500, 256, 0, stream>>>(h, w1, b1, nullptr, t1, stats + 0);
    k_bnfin<<<1, 64, 0, stream>>>(stats + 0, g1, bb1, ssb + 0);
    k_lin<64, true, true><<<2500, 256, 0, stream>>>(t1, w2, b2, ssb + 0, t2, stats + 128);
    k_bnfin<<<1, 64, 0, stream>>>(stats + 128, g2, bb2, ssb + 128);
    k_lin<64, true, true><<<2500, 256, 0, stream>>>(t2, w3, b3, ssb + 128, t1, stats + 256);
    k_bnfin<<<1, 64, 0, stream>>>(stats + 256, g3, bb3, ssb + 256);
    k_lin<64, true, false><<<2500, 256, 0, stream>>>(t1, w4, b4, ssb + 256, t2, nullptr);
    k_bounds<<<1, 128, 0, stream>>>(batch, start);
    k_pool<<<B_GRAPHS * 4, 256, 0, stream>>>(t2, start, gsum);
    k_head<<<1, 64, 0, stream>>>(gsum, start, action, pinw, pinb, phw, phb, pow_, pob,
                                 (float*)d_out);
}

// Round 4
// 1381.167 us; speedup vs baseline: 7.8856x; 7.8856x over previous
//
#include <hip/hip_runtime.h>
#include <cstdint>
#include <cstddef>

// CriticGNN: GENConv(softmax aggr) + MLP/BN + mean-pool + head. All fp32.
// R3 profile: k_edge = 94% of 10.9ms, VALUBusy 0.6%, WRITE_SIZE 6.4GB ->
// scattered fp32 atomics write through to HBM at ~32B/atomic. R4: build a
// dst-CSR (hist+scan+scatter, 3.2M int atomics on 400KB instead of 204.8M
// fp32 atomics on 25.6MB), then an atomic-free gather pass with per-node
// register accumulation of sum(e^m) and sum(m*e^m). agg fused with +h root.

#define N_NODES 100000
#define N_EDGES 3200000
#define B_GRAPHS 64
#define F_INF 64
#define E_INF 16
#define A_DIM 13
#define H_DIM 32
#define O_DIM 64
#define EPS_GEN 1e-7f
#define EPS_BN 1e-5f

// ---- K1: node encoder h = x @ node_w + node_b  [N,64]x[64,32] -> [N,32]
__global__ __launch_bounds__(256) void k_node_enc(
        const float* __restrict__ x, const float* __restrict__ w,
        const float* __restrict__ b, float* __restrict__ h) {
    __shared__ float sW[F_INF * H_DIM];
    __shared__ float sB[H_DIM];
    __shared__ float sX[8 * F_INF];
    int tid = threadIdx.x;
    for (int i = tid; i < F_INF * H_DIM; i += 256) sW[i] = w[i];
    if (tid < H_DIM) sB[tid] = b[tid];
    int node0 = blockIdx.x * 8;
    const float2* xp = (const float2*)(x + (size_t)node0 * F_INF);
    float2 v = xp[tid];
    sX[2 * tid] = v.x;
    sX[2 * tid + 1] = v.y;
    __syncthreads();
    int nl = tid >> 5, ch = tid & 31;
    float acc = sB[ch];
    const float* xr = &sX[nl * F_INF];
#pragma unroll
    for (int k = 0; k < F_INF; k++) acc = fmaf(xr[k], sW[k * H_DIM + ch], acc);
    h[(size_t)(node0 + nl) * H_DIM + ch] = acc;
}

// ---- K2a: histogram of dst degrees
__global__ __launch_bounds__(256) void k_hist(
        const int* __restrict__ ei, int* __restrict__ deg) {
    int e = blockIdx.x * 256 + threadIdx.x;
    if (e >= N_EDGES) return;
    atomicAdd(&deg[ei[N_EDGES + e]], 1);
}

// ---- K2b: per-256-block inclusive scan of deg -> incl, block sums -> bsum
__global__ __launch_bounds__(256) void k_scan1(
        const int* __restrict__ deg, int* __restrict__ incl,
        int* __restrict__ bsum) {
    __shared__ int s[256];
    int tid = threadIdx.x;
    int i = blockIdx.x * 256 + tid;
    int v = (i < N_NODES) ? deg[i] : 0;
    s[tid] = v;
    __syncthreads();
    for (int d = 1; d < 256; d <<= 1) {
        int t = (tid >= d) ? s[tid - d] : 0;
        __syncthreads();
        s[tid] += t;
        __syncthreads();
    }
    if (i < N_NODES) incl[i] = s[tid];
    if (tid == 255) bsum[blockIdx.x] = s[255];
}

// ---- K2c: scan block sums (391 entries) in-place -> exclusive
#define SCAN_BLOCKS 391
__global__ __launch_bounds__(512) void k_scan2(int* __restrict__ bsum) {
    __shared__ int s[512];
    int t = threadIdx.x;
    int v = (t < SCAN_BLOCKS) ? bsum[t] : 0;
    s[t] = v;
    __syncthreads();
    for (int d = 1; d < 512; d <<= 1) {
        int tv = (t >= d) ? s[t - d] : 0;
        __syncthreads();
        s[t] += tv;
        __syncthreads();
    }
    if (t < SCAN_BLOCKS) bsum[t] = s[t] - v;  // exclusive
}

// ---- K2d: finalize offsets (into deg array) + cursor copy (into incl array)
__global__ __launch_bounds__(256) void k_scan3(
        int* __restrict__ deg_offs, int* __restrict__ incl_cursor,
        const int* __restrict__ bsum) {
    int i = blockIdx.x * 256 + threadIdx.x;
    if (i >= N_NODES) return;
    int o = bsum[i >> 8] + incl_cursor[i] - deg_offs[i];  // exclusive prefix
    deg_offs[i] = o;       // offs[i]
    incl_cursor[i] = o;    // cursor[i]
    if (i == 0) deg_offs[N_NODES] = N_EDGES;
}

// ---- K2e: scatter edge records into dst-sorted order
__global__ __launch_bounds__(256) void k_scatter(
        const int* __restrict__ ei, int* __restrict__ cursor,
        uint2* __restrict__ sorted) {
    int e = blockIdx.x * 256 + threadIdx.x;
    if (e >= N_EDGES) return;
    int src = ei[e];
    int d = ei[N_EDGES + e];
    int pos = atomicAdd(&cursor[d], 1);
    sorted[pos] = make_uint2((unsigned)e, (unsigned)src);
}

// ---- K3: atomic-free gather+softmax-aggregate+root-add.
// One wave per node; half-wave (32 lanes = 32 channels) per edge.
__global__ __launch_bounds__(256) void k_gather(
        const uint2* __restrict__ sorted, const int* __restrict__ offs,
        const float* __restrict__ ea, const float* __restrict__ ew,
        const float* __restrict__ eb, const float* __restrict__ h,
        float* __restrict__ conv) {
    __shared__ float sW[E_INF * H_DIM];
    __shared__ float sB[H_DIM];
    int tid = threadIdx.x;
    for (int i = tid; i < E_INF * H_DIM; i += 256) sW[i] = ew[i];
    if (tid < H_DIM) sB[tid] = eb[tid];
    __syncthreads();
    int wave = tid >> 6;
    int lane = tid & 63;
    int p = lane >> 5;     // half-wave id
    int j = lane & 31;     // channel
    int v = blockIdx.x * 4 + wave;   // grid = 25000 blocks, exact cover
    int s0 = offs[v], s1 = offs[v + 1];
    float hv = h[(size_t)v * H_DIM + j];
    float se = 0.0f, sme = 0.0f;
    for (int k = s0 + p; k < s1; k += 2) {
        uint2 es = sorted[k];                       // broadcast within half-wave
        const float4* eap = (const float4*)(ea + (size_t)es.x * E_INF);
        float acc = sB[j];
#pragma unroll
        for (int t = 0; t < 4; t++) {
            float4 q = eap[t];
            acc = fmaf(q.x, sW[(4 * t + 0) * H_DIM + j], acc);
            acc = fmaf(q.y, sW[(4 * t + 1) * H_DIM + j], acc);
            acc = fmaf(q.z, sW[(4 * t + 2) * H_DIM + j], acc);
            acc = fmaf(q.w, sW[(4 * t + 3) * H_DIM + j], acc);
        }
        float hs = h[(size_t)es.y * H_DIM + j];     // coalesced 128B per half-wave
        float m = fmaxf(acc + hs, 0.0f) + EPS_GEN;
        float ex = __expf(m);
        se += ex;
        sme += m * ex;
    }
    se += __shfl_xor(se, 32);
    sme += __shfl_xor(sme, 32);
    if (p == 0) {
        float r = (se > 0.0f) ? (sme / se) : 0.0f;
        conv[(size_t)v * H_DIM + j] = r + hv;
    }
}

// ---- K4: fused Lin (+optional folded-BN+ReLU on input) (+optional BN-stats)
template <int IN_CH, bool BN_IN, bool STATS>
__global__ __launch_bounds__(256) void k_lin(
        const float* __restrict__ in, const float* __restrict__ w,
        const float* __restrict__ b, const float* __restrict__ ss,
        float* __restrict__ out, float* __restrict__ stats) {
    __shared__ float sW[IN_CH * O_DIM];
    __shared__ float sB[O_DIM];
    __shared__ float sS[IN_CH], sH[IN_CH];
    __shared__ float sX[4 * IN_CH];
    __shared__ float r1[256], r2[256];
    int tid = threadIdx.x;
    for (int i = tid; i < IN_CH * O_DIM; i += 256) sW[i] = w[i];
    if (tid < O_DIM) sB[tid] = b[tid];
    if constexpr (BN_IN) {
        if (tid < IN_CH) { sS[tid] = ss[tid]; sH[tid] = ss[64 + tid]; }
    }
    int ch = tid & 63, nl = tid >> 6;
    float s1 = 0.0f, s2 = 0.0f;
    const int ngroups = N_NODES / 4;  // 25000
    __syncthreads();
    for (int g = blockIdx.x; g < ngroups; g += gridDim.x) {
        int node0 = g * 4;
        __syncthreads();
        for (int i = tid; i < 4 * IN_CH; i += 256) {
            float v = in[(size_t)node0 * IN_CH + i];
            if constexpr (BN_IN) {
                int c = i & (IN_CH - 1);
                v = fmaxf(fmaf(v, sS[c], sH[c]), 0.0f);
            }
            sX[i] = v;
        }
        __syncthreads();
        float acc = sB[ch];
        const float* xr = &sX[nl * IN_CH];
#pragma unroll
        for (int k = 0; k < IN_CH; k++) acc = fmaf(xr[k], sW[k * O_DIM + ch], acc);
        out[(size_t)(node0 + nl) * O_DIM + ch] = acc;
        if constexpr (STATS) { s1 += acc; s2 += acc * acc; }
    }
    if constexpr (STATS) {
        __syncthreads();
        r1[tid] = s1; r2[tid] = s2;
        __syncthreads();
        if (tid < 64) {
            float a1 = r1[tid] + r1[tid + 64] + r1[tid + 128] + r1[tid + 192];
            float a2 = r2[tid] + r2[tid + 64] + r2[tid + 128] + r2[tid + 192];
            unsafeAtomicAdd(&stats[tid], a1);
            unsafeAtomicAdd(&stats[64 + tid], a2);
        }
    }
}

// ---- K5: finalize BN stats -> folded scale/shift
__global__ void k_bnfin(const float* __restrict__ stats, const float* __restrict__ g,
                        const float* __restrict__ b, float* __restrict__ ss) {
    int c = threadIdx.x;
    if (c >= 64) return;
    const float invN = 1.0f / (float)N_NODES;
    float mu = stats[c] * invN;
    float var = fmaxf(stats[64 + c] * invN - mu * mu, 0.0f);
    float rs = 1.0f / sqrtf(var + EPS_BN);
    float sc = g[c] * rs;
    ss[c] = sc;
    ss[64 + c] = b[c] - mu * sc;
}

// ---- K6: graph boundaries via binary search over sorted batch
__global__ void k_bounds(const int* __restrict__ batch, int* __restrict__ start) {
    int g = threadIdx.x;
    if (g > B_GRAPHS) return;
    int lo = 0, hi = N_NODES;
    while (lo < hi) {
        int mid = (lo + hi) >> 1;
        if (batch[mid] < g) lo = mid + 1; else hi = mid;
    }
    start[g] = lo;
}

// ---- K7: segmented mean-pool partials (4 blocks per graph)
__global__ __launch_bounds__(256) void k_pool(
        const float* __restrict__ no, const int* __restrict__ start,
        float* __restrict__ gsum) {
    int g = blockIdx.x >> 2, q = blockIdx.x & 3;
    int s0 = start[g], s1e = start[g + 1];
    int len = s1e - s0;
    int per = (len + 3) >> 2;
    int a = s0 + q * per;
    int bnd = min(s0 + (q + 1) * per, s1e);
    int ch = threadIdx.x & 63, nl = threadIdx.x >> 6;
    float acc = 0.0f;
    for (int n = a + nl; n < bnd; n += 4) acc += no[(size_t)n * O_DIM + ch];
    __shared__ float r[256];
    r[threadIdx.x] = acc;
    __syncthreads();
    if (threadIdx.x < 64) {
        float v = r[ch] + r[ch + 64] + r[ch + 128] + r[ch + 192];
        unsafeAtomicAdd(&gsum[g * O_DIM + ch], v);
    }
}

// ---- K8: head (one thread per graph)
__global__ void k_head(const float* __restrict__ gsum, const int* __restrict__ start,
                       const float* __restrict__ action,
                       const float* __restrict__ pinw, const float* __restrict__ pinb,
                       const float* __restrict__ phw, const float* __restrict__ phb,
                       const float* __restrict__ pow_, const float* __restrict__ pob,
                       float* __restrict__ outp) {
    int g = threadIdx.x;
    if (g >= B_GRAPHS) return;
    int cnt = start[g + 1] - start[g];
    float inv = 1.0f / (float)max(cnt, 1);
    float mol[64];
#pragma unroll
    for (int c = 0; c < 64; c++) mol[c] = gsum[g * 64 + c] * inv;
    float fp[16];
#pragma unroll
    for (int j = 0; j < 16; j++) {
        float a = pinb[j];
        for (int c = 0; c < 64; c++) a = fmaf(mol[c], pinw[c * 16 + j], a);
        fp[j] = fmaxf(a, 0.0f);
    }
    float pol[10];
#pragma unroll
    for (int j = 0; j < 10; j++) {
        float a = phb[j];
        for (int k = 0; k < 16; k++) a = fmaf(fp[k], phw[k * 10 + j], a);
        for (int k = 0; k < 13; k++) a = fmaf(action[g * 13 + k], phw[(16 + k) * 10 + j], a);
        pol[j] = fmaxf(a, 0.0f);
    }
    float o = pob[0];
#pragma unroll
    for (int j = 0; j < 10; j++) o = fmaf(pol[j], pow_[j], o);
    outp[g] = o;
}

extern "C" void kernel_launch(void* const* d_in, const int* in_sizes, int n_in,
                              void* d_out, int out_size, void* d_ws, size_t ws_size,
                              hipStream_t stream) {
    const float* x      = (const float*)d_in[0];
    const int*   ei     = (const int*)d_in[1];
    const float* ea     = (const float*)d_in[2];
    const int*   batch  = (const int*)d_in[3];
    const float* action = (const float*)d_in[4];
    const float* node_w = (const float*)d_in[5];
    const float* node_b = (const float*)d_in[6];
    const float* edge_w = (const float*)d_in[7];
    const float* edge_b = (const float*)d_in[8];
    const float* w1 = (const float*)d_in[9];   const float* b1 = (const float*)d_in[10];
    const float* g1 = (const float*)d_in[11];  const float* bb1 = (const float*)d_in[12];
    const float* w2 = (const float*)d_in[13];  const float* b2 = (const float*)d_in[14];
    const float* g2 = (const float*)d_in[15];  const float* bb2 = (const float*)d_in[16];
    const float* w3 = (const float*)d_in[17];  const float* b3 = (const float*)d_in[18];
    const float* g3 = (const float*)d_in[19];  const float* bb3 = (const float*)d_in[20];
    const float* w4 = (const float*)d_in[21];  const float* b4 = (const float*)d_in[22];
    const float* pinw = (const float*)d_in[23]; const float* pinb = (const float*)d_in[24];
    const float* phw  = (const float*)d_in[25]; const float* phb  = (const float*)d_in[26];
    const float* pow_ = (const float*)d_in[27]; const float* pob  = (const float*)d_in[28];

    // ---- workspace layout (bytes, 256-aligned chunks). Total ~52 MB.
    char* wsb = (char*)d_ws;
    size_t off = 0;
    float* stats  = (float*)(wsb + off); off += 512 * 4;            // 2KB (zeroed)
    float* gsum   = (float*)(wsb + off); off += 4096 * 4;           // 16KB (zeroed)
    int*   offs   = (int*)  (wsb + off); off += 400128;             // deg->offs, N+1 (zeroed)
    size_t zero_bytes = off;                                        // 418.7KB
    int*   cursor = (int*)  (wsb + off); off += 400128;             // incl->cursor
    int*   bsum   = (int*)  (wsb + off); off += 2048;               // 512 ints
    float* ssb    = (float*)(wsb + off); off += 512 * 4;            // folded BN
    int*   start  = (int*)  (wsb + off); off += 512;
    uint2* sorted = (uint2*)(wsb + off); off += (size_t)N_EDGES * 8;     // 25.6MB
    float* h      = (float*)(wsb + off); off += (size_t)N_NODES * H_DIM * 4; // 12.8MB
    float* conv   = (float*)(wsb + off); off += (size_t)N_NODES * H_DIM * 4; // 12.8MB
    float* t1 = (float*)sorted;  // 25.6MB overlay (sorted dead after k_gather)
    float* t2 = h;               // 25.6MB overlay (h+conv dead after MLP-P1)

    hipMemsetAsync(d_ws, 0, zero_bytes, stream);

    k_node_enc<<<N_NODES / 8, 256, 0, stream>>>(x, node_w, node_b, h);
    // build dst-CSR
    k_hist<<<(N_EDGES + 255) / 256, 256, 0, stream>>>(ei, offs);
    k_scan1<<<SCAN_BLOCKS, 256, 0, stream>>>(offs, cursor, bsum);
    k_scan2<<<1, 512, 0, stream>>>(bsum);
    k_scan3<<<SCAN_BLOCKS, 256, 0, stream>>>(offs, cursor, bsum);
    k_scatter<<<(N_EDGES + 255) / 256, 256, 0, stream>>>(ei, cursor, sorted);
    // atomic-free aggregation (fuses softmax-agg + root add)
    k_gather<<<N_NODES / 4, 256, 0, stream>>>(sorted, offs, ea, edge_w, edge_b, h, conv);
    // MLP: P1 32->64 (stats1), P2/P3 64->64 (bn in, stats), P4 64->64 (bn in)
    k_lin<32, false, true><<<2500, 256, 0, stream>>>(conv, w1, b1, nullptr, t1, stats + 0);
    k_bnfin<<<1, 64, 0, stream>>>(stats + 0, g1, bb1, ssb + 0);
    k_lin<64, true, true><<<2500, 256, 0, stream>>>(t1, w2, b2, ssb + 0, t2, stats + 128);
    k_bnfin<<<1, 64, 0, stream>>>(stats + 128, g2, bb2, ssb + 128);
    k_lin<64, true, true><<<2500, 256, 0, stream>>>(t2, w3, b3, ssb + 128, t1, stats + 256);
    k_bnfin<<<1, 64, 0, stream>>>(stats + 256, g3, bb3, ssb + 256);
    k_lin<64, true, false><<<2500, 256, 0, stream>>>(t1, w4, b4, ssb + 256, t2, nullptr);
    k_bounds<<<1, 128, 0, stream>>>(batch, start);
    k_pool<<<B_GRAPHS * 4, 256, 0, stream>>>(t2, start, gsum);
    k_head<<<1, 64, 0, stream>>>(gsum, start, action, pinw, pinb, phw, phb, pow_, pob,
                                 (float*)d_out);
}

// Round 5
// 1198.306 us; speedup vs baseline: 9.0890x; 1.1526x over previous
//
#include <hip/hip_runtime.h>
#include <cstdint>
#include <cstddef>

// CriticGNN: GENConv(softmax aggr) + MLP/BN + mean-pool + head. All fp32.
// R4 profile: k_gather 348us, FETCH 393MB @15% HBM, VALUBusy 29% ->
// latency-bound random 64B ea[eid] reads. R5: (a) permute ea into dst order
// during scatter (streaming gather reads; needs ~245MB ws, fallback to
// indexed path if ws too small), (b) 2-deep prefetch pipeline in gather,
// (c) k_lin restaged at 16 nodes/iter.

#define N_NODES 100000
#define N_EDGES 3200000
#define B_GRAPHS 64
#define F_INF 64
#define E_INF 16
#define A_DIM 13
#define H_DIM 32
#define O_DIM 64
#define EPS_GEN 1e-7f
#define EPS_BN 1e-5f
#define SCAN_BLOCKS 391

// ---- K1: node encoder h = x @ node_w + node_b  [N,64]x[64,32] -> [N,32]
__global__ __launch_bounds__(256) void k_node_enc(
        const float* __restrict__ x, const float* __restrict__ w,
        const float* __restrict__ b, float* __restrict__ h) {
    __shared__ float sW[F_INF * H_DIM];
    __shared__ float sB[H_DIM];
    __shared__ float sX[8 * F_INF];
    int tid = threadIdx.x;
    for (int i = tid; i < F_INF * H_DIM; i += 256) sW[i] = w[i];
    if (tid < H_DIM) sB[tid] = b[tid];
    int node0 = blockIdx.x * 8;
    const float2* xp = (const float2*)(x + (size_t)node0 * F_INF);
    float2 v = xp[tid];
    sX[2 * tid] = v.x;
    sX[2 * tid + 1] = v.y;
    __syncthreads();
    int nl = tid >> 5, ch = tid & 31;
    float acc = sB[ch];
    const float* xr = &sX[nl * F_INF];
#pragma unroll
    for (int k = 0; k < F_INF; k++) acc = fmaf(xr[k], sW[k * H_DIM + ch], acc);
    h[(size_t)(node0 + nl) * H_DIM + ch] = acc;
}

// ---- K2a: histogram of dst degrees (int4-vectorized reads)
__global__ __launch_bounds__(256) void k_hist(
        const int* __restrict__ ei, int* __restrict__ deg) {
    int i = blockIdx.x * 256 + threadIdx.x;
    if (i >= N_EDGES / 4) return;
    int4 d = ((const int4*)(ei + N_EDGES))[i];
    atomicAdd(&deg[d.x], 1);
    atomicAdd(&deg[d.y], 1);
    atomicAdd(&deg[d.z], 1);
    atomicAdd(&deg[d.w], 1);
}

// ---- K2b: per-256-block inclusive scan of deg -> incl, block sums -> bsum
__global__ __launch_bounds__(256) void k_scan1(
        const int* __restrict__ deg, int* __restrict__ incl,
        int* __restrict__ bsum) {
    __shared__ int s[256];
    int tid = threadIdx.x;
    int i = blockIdx.x * 256 + tid;
    int v = (i < N_NODES) ? deg[i] : 0;
    s[tid] = v;
    __syncthreads();
    for (int d = 1; d < 256; d <<= 1) {
        int t = (tid >= d) ? s[tid - d] : 0;
        __syncthreads();
        s[tid] += t;
        __syncthreads();
    }
    if (i < N_NODES) incl[i] = s[tid];
    if (tid == 255) bsum[blockIdx.x] = s[255];
}

// ---- K2c: scan block sums in-place -> exclusive
__global__ __launch_bounds__(512) void k_scan2(int* __restrict__ bsum) {
    __shared__ int s[512];
    int t = threadIdx.x;
    int v = (t < SCAN_BLOCKS) ? bsum[t] : 0;
    s[t] = v;
    __syncthreads();
    for (int d = 1; d < 512; d <<= 1) {
        int tv = (t >= d) ? s[t - d] : 0;
        __syncthreads();
        s[t] += tv;
        __syncthreads();
    }
    if (t < SCAN_BLOCKS) bsum[t] = s[t] - v;  // exclusive
}

// ---- K2d: finalize offsets (into deg array) + cursor copy (into incl array)
__global__ __launch_bounds__(256) void k_scan3(
        int* __restrict__ deg_offs, int* __restrict__ incl_cursor,
        const int* __restrict__ bsum) {
    int i = blockIdx.x * 256 + threadIdx.x;
    if (i >= N_NODES) return;
    int o = bsum[i >> 8] + incl_cursor[i] - deg_offs[i];  // exclusive prefix
    deg_offs[i] = o;
    incl_cursor[i] = o;
    if (i == 0) deg_offs[N_NODES] = N_EDGES;
}

// ---- K2e-A: scatter with ea permutation (streaming-gather path)
__global__ __launch_bounds__(256) void k_scatter_perm(
        const int* __restrict__ ei, int* __restrict__ cursor,
        const float* __restrict__ ea, float* __restrict__ eap,
        int* __restrict__ srcp) {
    int e = blockIdx.x * 256 + threadIdx.x;
    if (e >= N_EDGES) return;
    int src = ei[e];
    int d = ei[N_EDGES + e];
    const float4* er = (const float4*)(ea + (size_t)e * E_INF);
    float4 q0 = er[0], q1 = er[1], q2 = er[2], q3 = er[3];
    int pos = atomicAdd(&cursor[d], 1);
    float4* wr = (float4*)(eap + (size_t)pos * E_INF);
    wr[0] = q0; wr[1] = q1; wr[2] = q2; wr[3] = q3;
    srcp[pos] = src;
}

// ---- K2e-B: scatter edge records only (indexed-gather fallback)
__global__ __launch_bounds__(256) void k_scatter_idx(
        const int* __restrict__ ei, int* __restrict__ cursor,
        uint2* __restrict__ sorted) {
    int e = blockIdx.x * 256 + threadIdx.x;
    if (e >= N_EDGES) return;
    int src = ei[e];
    int d = ei[N_EDGES + e];
    int pos = atomicAdd(&cursor[d], 1);
    sorted[pos] = make_uint2((unsigned)e, (unsigned)src);
}

// ---- K3: atomic-free gather + softmax-aggregate + root-add.
// One wave per node; half-wave (32 lanes = 32 channels) per edge.
// 2-deep software pipeline on the per-edge loads.
// PERM: ea rows pre-permuted to dst order (streaming); else indexed by eid.
template <bool PERM>
__global__ __launch_bounds__(256) void k_gather(
        const float* __restrict__ easrc, const int* __restrict__ srcp,
        const uint2* __restrict__ sorted, const int* __restrict__ offs,
        const float* __restrict__ ew, const float* __restrict__ eb,
        const float* __restrict__ h, float* __restrict__ conv) {
    __shared__ float sW[E_INF * H_DIM];
    __shared__ float sB[H_DIM];
    int tid = threadIdx.x;
    for (int i = tid; i < E_INF * H_DIM; i += 256) sW[i] = ew[i];
    if (tid < H_DIM) sB[tid] = eb[tid];
    __syncthreads();
    int wave = tid >> 6;
    int lane = tid & 63;
    int p = lane >> 5;     // half-wave id
    int j = lane & 31;     // channel
    int v = blockIdx.x * 4 + wave;   // grid 25000 -> exact cover
    int s0 = offs[v], s1 = offs[v + 1];
    float hv = h[(size_t)v * H_DIM + j];
    float se = 0.0f, sme = 0.0f;

    int k = s0 + p;
    float4 q0, q1, q2, q3;
    int sc = 0;
    if (k < s1) {
        const float4* er;
        if constexpr (PERM) {
            er = (const float4*)(easrc + (size_t)k * E_INF);
            sc = srcp[k];
        } else {
            uint2 es = sorted[k];
            er = (const float4*)(easrc + (size_t)es.x * E_INF);
            sc = (int)es.y;
        }
        q0 = er[0]; q1 = er[1]; q2 = er[2]; q3 = er[3];
    }
    while (k < s1) {
        int kn = k + 2;
        float4 n0, n1, n2, n3;
        int nsc = 0;
        if (kn < s1) {
            const float4* er;
            if constexpr (PERM) {
                er = (const float4*)(easrc + (size_t)kn * E_INF);
                nsc = srcp[kn];
            } else {
                uint2 es = sorted[kn];
                er = (const float4*)(easrc + (size_t)es.x * E_INF);
                nsc = (int)es.y;
            }
            n0 = er[0]; n1 = er[1]; n2 = er[2]; n3 = er[3];
        }
        float hs = h[(size_t)sc * H_DIM + j];
        float acc = sB[j];
        acc = fmaf(q0.x, sW[0 * H_DIM + j], acc);
        acc = fmaf(q0.y, sW[1 * H_DIM + j], acc);
        acc = fmaf(q0.z, sW[2 * H_DIM + j], acc);
        acc = fmaf(q0.w, sW[3 * H_DIM + j], acc);
        acc = fmaf(q1.x, sW[4 * H_DIM + j], acc);
        acc = fmaf(q1.y, sW[5 * H_DIM + j], acc);
        acc = fmaf(q1.z, sW[6 * H_DIM + j], acc);
        acc = fmaf(q1.w, sW[7 * H_DIM + j], acc);
        acc = fmaf(q2.x, sW[8 * H_DIM + j], acc);
        acc = fmaf(q2.y, sW[9 * H_DIM + j], acc);
        acc = fmaf(q2.z, sW[10 * H_DIM + j], acc);
        acc = fmaf(q2.w, sW[11 * H_DIM + j], acc);
        acc = fmaf(q3.x, sW[12 * H_DIM + j], acc);
        acc = fmaf(q3.y, sW[13 * H_DIM + j], acc);
        acc = fmaf(q3.z, sW[14 * H_DIM + j], acc);
        acc = fmaf(q3.w, sW[15 * H_DIM + j], acc);
        float m = fmaxf(acc + hs, 0.0f) + EPS_GEN;
        float ex = __expf(m);
        se += ex;
        sme += m * ex;
        q0 = n0; q1 = n1; q2 = n2; q3 = n3; sc = nsc;
        k = kn;
    }
    se += __shfl_xor(se, 32);
    sme += __shfl_xor(sme, 32);
    if (p == 0) {
        float r = (se > 0.0f) ? (sme / se) : 0.0f;
        conv[(size_t)v * H_DIM + j] = r + hv;
    }
}

// ---- K4: fused Lin (+optional folded-BN+ReLU on input) (+optional BN-stats)
// 16 nodes per stage iteration: 2 syncs per 1024 FMA/thread-block-iter.
template <int IN_CH, bool BN_IN, bool STATS>
__global__ __launch_bounds__(256) void k_lin(
        const float* __restrict__ in, const float* __restrict__ w,
        const float* __restrict__ b, const float* __restrict__ ss,
        float* __restrict__ out, float* __restrict__ stats) {
    __shared__ float sW[IN_CH * O_DIM];
    __shared__ float sB[O_DIM];
    __shared__ float sS[IN_CH], sH[IN_CH];
    __shared__ float sX[16 * IN_CH];
    __shared__ float r1[256], r2[256];
    int tid = threadIdx.x;
    for (int i = tid; i < IN_CH * O_DIM; i += 256) sW[i] = w[i];
    if (tid < O_DIM) sB[tid] = b[tid];
    if constexpr (BN_IN) {
        if (tid < IN_CH) { sS[tid] = ss[tid]; sH[tid] = ss[64 + tid]; }
    }
    int ch = tid & 63, nl = tid >> 6;
    float s1 = 0.0f, s2 = 0.0f;
    const int ngroups = N_NODES / 16;  // 6250
    __syncthreads();
    for (int g = blockIdx.x; g < ngroups; g += gridDim.x) {
        size_t base = (size_t)g * 16 * IN_CH;
        __syncthreads();
        if constexpr (IN_CH == 64) {
            float4 v = ((const float4*)(in + base))[tid];
            if constexpr (BN_IN) {
                int c0 = (tid * 4) & 63;
                v.x = fmaxf(fmaf(v.x, sS[c0], sH[c0]), 0.0f);
                v.y = fmaxf(fmaf(v.y, sS[c0 + 1], sH[c0 + 1]), 0.0f);
                v.z = fmaxf(fmaf(v.z, sS[c0 + 2], sH[c0 + 2]), 0.0f);
                v.w = fmaxf(fmaf(v.w, sS[c0 + 3], sH[c0 + 3]), 0.0f);
            }
            ((float4*)sX)[tid] = v;
        } else {
            float2 v = ((const float2*)(in + base))[tid];
            if constexpr (BN_IN) {
                int c0 = (tid * 2) & (IN_CH - 1);
                v.x = fmaxf(fmaf(v.x, sS[c0], sH[c0]), 0.0f);
                v.y = fmaxf(fmaf(v.y, sS[c0 + 1], sH[c0 + 1]), 0.0f);
            }
            ((float2*)sX)[tid] = v;
        }
        __syncthreads();
#pragma unroll
        for (int q = 0; q < 4; q++) {
            const float* xr = &sX[(nl + 4 * q) * IN_CH];
            float acc = sB[ch];
#pragma unroll
            for (int k = 0; k < IN_CH; k++) acc = fmaf(xr[k], sW[k * O_DIM + ch], acc);
            out[(size_t)(g * 16 + nl + 4 * q) * O_DIM + ch] = acc;
            if constexpr (STATS) { s1 += acc; s2 += acc * acc; }
        }
    }
    if constexpr (STATS) {
        __syncthreads();
        r1[tid] = s1; r2[tid] = s2;
        __syncthreads();
        if (tid < 64) {
            float a1 = r1[tid] + r1[tid + 64] + r1[tid + 128] + r1[tid + 192];
            float a2 = r2[tid] + r2[tid + 64] + r2[tid + 128] + r2[tid + 192];
            unsafeAtomicAdd(&stats[tid], a1);
            unsafeAtomicAdd(&stats[64 + tid], a2);
        }
    }
}

// ---- K5: finalize BN stats -> folded scale/shift
__global__ void k_bnfin(const float* __restrict__ stats, const float* __restrict__ g,
                        const float* __restrict__ b, float* __restrict__ ss) {
    int c = threadIdx.x;
    if (c >= 64) return;
    const float invN = 1.0f / (float)N_NODES;
    float mu = stats[c] * invN;
    float var = fmaxf(stats[64 + c] * invN - mu * mu, 0.0f);
    float rs = 1.0f / sqrtf(var + EPS_BN);
    float sc = g[c] * rs;
    ss[c] = sc;
    ss[64 + c] = b[c] - mu * sc;
}

// ---- K6: graph boundaries via binary search over sorted batch
__global__ void k_bounds(const int* __restrict__ batch, int* __restrict__ start) {
    int g = threadIdx.x;
    if (g > B_GRAPHS) return;
    int lo = 0, hi = N_NODES;
    while (lo < hi) {
        int mid = (lo + hi) >> 1;
        if (batch[mid] < g) lo = mid + 1; else hi = mid;
    }
    start[g] = lo;
}

// ---- K7: segmented mean-pool partials (4 blocks per graph)
__global__ __launch_bounds__(256) void k_pool(
        const float* __restrict__ no, const int* __restrict__ start,
        float* __restrict__ gsum) {
    int g = blockIdx.x >> 2, q = blockIdx.x & 3;
    int s0 = start[g], s1e = start[g + 1];
    int len = s1e - s0;
    int per = (len + 3) >> 2;
    int a = s0 + q * per;
    int bnd = min(s0 + (q + 1) * per, s1e);
    int ch = threadIdx.x & 63, nl = threadIdx.x >> 6;
    float acc = 0.0f;
    for (int n = a + nl; n < bnd; n += 4) acc += no[(size_t)n * O_DIM + ch];
    __shared__ float r[256];
    r[threadIdx.x] = acc;
    __syncthreads();
    if (threadIdx.x < 64) {
        float v = r[ch] + r[ch + 64] + r[ch + 128] + r[ch + 192];
        unsafeAtomicAdd(&gsum[g * O_DIM + ch], v);
    }
}

// ---- K8: head (one thread per graph)
__global__ void k_head(const float* __restrict__ gsum, const int* __restrict__ start,
                       const float* __restrict__ action,
                       const float* __restrict__ pinw, const float* __restrict__ pinb,
                       const float* __restrict__ phw, const float* __restrict__ phb,
                       const float* __restrict__ pow_, const float* __restrict__ pob,
                       float* __restrict__ outp) {
    int g = threadIdx.x;
    if (g >= B_GRAPHS) return;
    int cnt = start[g + 1] - start[g];
    float inv = 1.0f / (float)max(cnt, 1);
    float mol[64];
#pragma unroll
    for (int c = 0; c < 64; c++) mol[c] = gsum[g * 64 + c] * inv;
    float fp[16];
#pragma unroll
    for (int j = 0; j < 16; j++) {
        float a = pinb[j];
        for (int c = 0; c < 64; c++) a = fmaf(mol[c], pinw[c * 16 + j], a);
        fp[j] = fmaxf(a, 0.0f);
    }
    float pol[10];
#pragma unroll
    for (int j = 0; j < 10; j++) {
        float a = phb[j];
        for (int k = 0; k < 16; k++) a = fmaf(fp[k], phw[k * 10 + j], a);
        for (int k = 0; k < 13; k++) a = fmaf(action[g * 13 + k], phw[(16 + k) * 10 + j], a);
        pol[j] = fmaxf(a, 0.0f);
    }
    float o = pob[0];
#pragma unroll
    for (int j = 0; j < 10; j++) o = fmaf(pol[j], pow_[j], o);
    outp[g] = o;
}

extern "C" void kernel_launch(void* const* d_in, const int* in_sizes, int n_in,
                              void* d_out, int out_size, void* d_ws, size_t ws_size,
                              hipStream_t stream) {
    const float* x      = (const float*)d_in[0];
    const int*   ei     = (const int*)d_in[1];
    const float* ea     = (const float*)d_in[2];
    const int*   batch  = (const int*)d_in[3];
    const float* action = (const float*)d_in[4];
    const float* node_w = (const float*)d_in[5];
    const float* node_b = (const float*)d_in[6];
    const float* edge_w = (const float*)d_in[7];
    const float* edge_b = (const float*)d_in[8];
    const float* w1 = (const float*)d_in[9];   const float* b1 = (const float*)d_in[10];
    const float* g1 = (const float*)d_in[11];  const float* bb1 = (const float*)d_in[12];
    const float* w2 = (const float*)d_in[13];  const float* b2 = (const float*)d_in[14];
    const float* g2 = (const float*)d_in[15];  const float* bb2 = (const float*)d_in[16];
    const float* w3 = (const float*)d_in[17];  const float* b3 = (const float*)d_in[18];
    const float* g3 = (const float*)d_in[19];  const float* bb3 = (const float*)d_in[20];
    const float* w4 = (const float*)d_in[21];  const float* b4 = (const float*)d_in[22];
    const float* pinw = (const float*)d_in[23]; const float* pinb = (const float*)d_in[24];
    const float* phw  = (const float*)d_in[25]; const float* phb  = (const float*)d_in[26];
    const float* pow_ = (const float*)d_in[27]; const float* pob  = (const float*)d_in[28];

    // ---- common workspace prefix
    char* wsb = (char*)d_ws;
    size_t off = 0;
    float* stats  = (float*)(wsb + off); off += 512 * 4;       // zeroed
    float* gsum   = (float*)(wsb + off); off += 4096 * 4;      // zeroed
    int*   offs   = (int*)  (wsb + off); off += 400128;        // deg->offs (zeroed)
    size_t zero_bytes = off;
    int*   cursor = (int*)  (wsb + off); off += 400128;
    int*   bsum   = (int*)  (wsb + off); off += 2048;
    float* ssb    = (float*)(wsb + off); off += 512 * 4;
    int*   start  = (int*)  (wsb + off); off += 512;
    int*   srcp   = (int*)  (wsb + off); off += (size_t)N_EDGES * 4;         // 12.8MB
    float* h      = (float*)(wsb + off); off += (size_t)N_NODES * H_DIM * 4; // 12.8MB
    float* conv   = (float*)(wsb + off); off += (size_t)N_NODES * H_DIM * 4; // 12.8MB
    size_t tail = off;
    // Path A: ea_perm (204.8MB) at tail; t1/t2 overlay it after gather.
    // Path B: sorted (25.6MB) at tail; t1 overlays sorted, t2 overlays h+conv.
    bool perm = (ws_size >= tail + (size_t)N_EDGES * E_INF * 4);
    float* eap    = (float*)(wsb + tail);
    uint2* sorted = (uint2*)(wsb + tail);
    float* t1, *t2;
    if (perm) {
        t1 = eap;                          // 25.6MB into ea_perm
        t2 = eap + (size_t)N_NODES * O_DIM;
    } else {
        t1 = (float*)sorted;               // 25.6MB overlay
        t2 = h;                            // 25.6MB spans h+conv
    }

    hipMemsetAsync(d_ws, 0, zero_bytes, stream);

    k_node_enc<<<N_NODES / 8, 256, 0, stream>>>(x, node_w, node_b, h);
    // build dst-CSR
    k_hist<<<(N_EDGES / 4 + 255) / 256, 256, 0, stream>>>(ei, offs);
    k_scan1<<<SCAN_BLOCKS, 256, 0, stream>>>(offs, cursor, bsum);
    k_scan2<<<1, 512, 0, stream>>>(bsum);
    k_scan3<<<SCAN_BLOCKS, 256, 0, stream>>>(offs, cursor, bsum);
    if (perm) {
        k_scatter_perm<<<(N_EDGES + 255) / 256, 256, 0, stream>>>(ei, cursor, ea, eap, srcp);
        k_gather<true><<<N_NODES / 4, 256, 0, stream>>>(eap, srcp, nullptr, offs,
                                                        edge_w, edge_b, h, conv);
    } else {
        k_scatter_idx<<<(N_EDGES + 255) / 256, 256, 0, stream>>>(ei, cursor, sorted);
        k_gather<false><<<N_NODES / 4, 256, 0, stream>>>(ea, nullptr, sorted, offs,
                                                         edge_w, edge_b, h, conv);
    }
    // MLP: P1 32->64 (stats1), P2/P3 64->64 (bn in, stats), P4 64->64 (bn in)
    k_lin<32, false, true><<<1250, 256, 0, stream>>>(conv, w1, b1, nullptr, t1, stats + 0);
    k_bnfin<<<1, 64, 0, stream>>>(stats + 0, g1, bb1, ssb + 0);
    k_lin<64, true, true><<<1250, 256, 0, stream>>>(t1, w2, b2, ssb + 0, t2, stats + 128);
    k_bnfin<<<1, 64, 0, stream>>>(stats + 128, g2, bb2, ssb + 128);
    k_lin<64, true, true><<<1250, 256, 0, stream>>>(t2, w3, b3, ssb + 128, t1, stats + 256);
    k_bnfin<<<1, 64, 0, stream>>>(stats + 256, g3, bb3, ssb + 256);
    k_lin<64, true, false><<<1250, 256, 0, stream>>>(t1, w4, b4, ssb + 256, t2, nullptr);
    k_bounds<<<1, 128, 0, stream>>>(batch, start);
    k_pool<<<B_GRAPHS * 4, 256, 0, stream>>>(t2, start, gsum);
    k_head<<<1, 64, 0, stream>>>(gsum, start, action, pinw, pinb, phw, phb, pow_, pob,
                                 (float*)d_out);
}